// Round 2
// baseline (1027.163 us; speedup 1.0000x reference)
//
#include <hip/hip_runtime.h>
#include <hip/hip_bf16.h>

#define DIM 256
#define HW  1024  // 32*32

// ---------------------------------------------------------------------------
// Dtype detector: flag=1 if inputs are fp32, 0 if bf16.
// fp32 buffers viewed as ushorts contain mantissa-halves with random exponent
// patterns -> ~16 NaN/Inf-pattern hits per 8192; real bf16 N(0,1) data: 0.
// ---------------------------------------------------------------------------
__global__ void detect_kernel(const unsigned short* __restrict__ xr,
                              int* __restrict__ flag) {
  __shared__ int cnt;
  if (threadIdx.x == 0) cnt = 0;
  __syncthreads();
  int local = 0;
  for (int i = threadIdx.x; i < 8192; i += 256) {
    unsigned short u = xr[i];
    if ((u & 0x7F80u) == 0x7F80u) local++;
  }
  if (local) atomicAdd(&cnt, local);
  __syncthreads();
  if (threadIdx.x == 0) *flag = (cnt > 0) ? 1 : 0;
}

__device__ inline float ldin(const void* p, long i, int isf32) {
  if (isf32) return ((const float*)p)[i];
  union { unsigned u; float f; } v;
  v.u = ((unsigned)((const unsigned short*)p)[i]) << 16;
  return v.f;
}

// Generic element converter (used for x and the biases)
__global__ void convert_kernel(const void* __restrict__ src,
                               float* __restrict__ dst, int n,
                               const int* __restrict__ flag) {
  const int isf32 = *flag;
  int i = blockIdx.x * 256 + threadIdx.x;
  if (i < n) dst[i] = ldin(src, i, isf32);
}

// Weight transpose + convert: w [O=256][I=256][KK] -> wT [KK][I=256][O=256]
__global__ void wtrans_kernel(const void* __restrict__ w,
                              float* __restrict__ wT, int KK,
                              const int* __restrict__ flag) {
  const int isf32 = *flag;
  int idx = blockIdx.x * 256 + threadIdx.x;
  int total = DIM * DIM * KK;
  if (idx >= total) return;
  int co = idx & 255;
  int ci = (idx >> 8) & 255;
  int kk = idx >> 16;
  wT[idx] = ldin(w, (long)(co * DIM + ci) * KK + kk, isf32);
}

// ---------------------------------------------------------------------------
// Implicit-GEMM conv, SAME padding, stride 1.  (verified by inspection R1)
//   x   : [B=8][32][32][256]  (NHWC, canonical fp32)
//   wT  : [KS*KS][256 ci][256 co]
//   out : TSTORE==0 -> NCHW [B][256][1024]   (q)
//         TSTORE==1 -> attention-transposed slab layout (k, v):
//                      out[(b*16+h)*16384 + d*1024 + m],
//                      h=co>>4, d=n&15, m=(co&15)*64 + (n>>4)
// ---------------------------------------------------------------------------
template <int KS, int TSTORE>
__global__ __launch_bounds__(256) void conv_kernel(
    const float* __restrict__ x, const float* __restrict__ wT,
    const float* __restrict__ bias, float* __restrict__ out) {
  constexpr int P = KS / 2;
  __shared__ float As[16][64];  // [k][m]
  __shared__ float Bs[16][64];  // [k][n]
  const int t   = threadIdx.x;
  const int b   = blockIdx.x >> 4;
  const int hh0 = (blockIdx.x & 15) << 1;
  const int co0 = blockIdx.y << 6;
  const int tx = t & 15;
  const int ty = t >> 4;
  const int pA  = t >> 2;
  const int cgA = (t & 3) << 2;
  const int rA = pA >> 5;
  const int cA = pA & 31;
  const int ciB  = t >> 4;
  const int co4B = (t & 15) << 2;

  float acc[4][4] = {{0.f, 0.f, 0.f, 0.f}};

  for (int kh = 0; kh < KS; ++kh) {
    const int hx = hh0 + rA + kh - P;
    for (int kw = 0; kw < KS; ++kw) {
      const int wx = cA + kw - P;
      const bool ok = ((unsigned)hx < 32u) && ((unsigned)wx < 32u);
      const float* xb = x + (((b * 32 + hx) * 32 + wx) * DIM);
      const float* wb = wT + ((kh * KS + kw) * (DIM * DIM));
      for (int c0 = 0; c0 < DIM; c0 += 16) {
        float4 av = make_float4(0.f, 0.f, 0.f, 0.f);
        if (ok) av = *(const float4*)(xb + c0 + cgA);
        const float4 bv = *(const float4*)(wb + (c0 + ciB) * DIM + co0 + co4B);
        __syncthreads();
        As[cgA + 0][pA] = av.x;
        As[cgA + 1][pA] = av.y;
        As[cgA + 2][pA] = av.z;
        As[cgA + 3][pA] = av.w;
        *(float4*)&Bs[ciB][co4B] = bv;
        __syncthreads();
#pragma unroll
        for (int kk = 0; kk < 16; ++kk) {
          const float4 a  = *(const float4*)&As[kk][tx << 2];
          const float4 bb = *(const float4*)&Bs[kk][ty << 2];
          acc[0][0] += a.x * bb.x; acc[0][1] += a.x * bb.y;
          acc[0][2] += a.x * bb.z; acc[0][3] += a.x * bb.w;
          acc[1][0] += a.y * bb.x; acc[1][1] += a.y * bb.y;
          acc[1][2] += a.y * bb.z; acc[1][3] += a.y * bb.w;
          acc[2][0] += a.z * bb.x; acc[2][1] += a.z * bb.y;
          acc[2][2] += a.z * bb.z; acc[2][3] += a.z * bb.w;
          acc[3][0] += a.w * bb.x; acc[3][1] += a.w * bb.y;
          acc[3][2] += a.w * bb.z; acc[3][3] += a.w * bb.w;
        }
      }
    }
  }
  const int p0 = tx << 2;
  const int n0 = (hh0 + (p0 >> 5)) * 32 + (p0 & 31);
#pragma unroll
  for (int j = 0; j < 4; ++j) {
    const int co = co0 + (ty << 2) + j;
    const float bj = bias[co];
    float vals[4] = {acc[0][j] + bj, acc[1][j] + bj, acc[2][j] + bj,
                     acc[3][j] + bj};
    if (TSTORE == 0) {
      *(float4*)&out[((b << 8) + co) * HW + n0] =
          make_float4(vals[0], vals[1], vals[2], vals[3]);
    } else {
      const int h   = co >> 4;
      const int clo = co & 15;
      const int base = (((b << 4) + h) << 14);
#pragma unroll
      for (int i = 0; i < 4; ++i) {
        const int n = n0 + i;
        out[base + ((n & 15) << 10) + (clo << 6) + (n >> 4)] = vals[i];
      }
    }
  }
}

// ---------------------------------------------------------------------------
// Attention per (b,h) slab: softmax(Q K^T * 0.25) V.   (verified R1)
// ---------------------------------------------------------------------------
__global__ __launch_bounds__(256) void attn_kernel(
    const float* __restrict__ q, const float* __restrict__ kT,
    const float* __restrict__ vT, float* __restrict__ out2) {
  __shared__ float Kc[16][256];
  __shared__ float Vc[16][256];
  __shared__ float red[4][64][20];
  const int t    = threadIdx.x;
  const int w    = t >> 6;
  const int lane = t & 63;
  const int slab = blockIdx.x >> 6;
  const int rb   = blockIdx.x & 63;
  const int b = slab >> 4;
  const int h = slab & 15;
  const float* Qs = q  + slab * 16384;
  const float* Ks = kT + slab * 16384;
  const float* Vs = vT + slab * 16384;
  const int row0 = (rb << 4) + (w << 2);

  float qr[4][16];
#pragma unroll
  for (int r = 0; r < 4; ++r) {
#pragma unroll
    for (int d4 = 0; d4 < 16; d4 += 4) {
      const float4 qv = *(const float4*)&Qs[(row0 + r) * 16 + d4];
      qr[r][d4 + 0] = qv.x; qr[r][d4 + 1] = qv.y;
      qr[r][d4 + 2] = qv.z; qr[r][d4 + 3] = qv.w;
    }
  }
  float o[4][16] = {};
  float l[4] = {0.f, 0.f, 0.f, 0.f};
  const float sc = 0.25f * 1.4426950408889634f;

  for (int c0 = 0; c0 < 1024; c0 += 256) {
    __syncthreads();
#pragma unroll
    for (int i = 0; i < 4; ++i) {
      const int f  = (i << 8) + t;
      const int d  = f >> 6;
      const int m4 = (f & 63) << 2;
      *(float4*)&Kc[d][m4] = *(const float4*)&Ks[d * 1024 + c0 + m4];
      *(float4*)&Vc[d][m4] = *(const float4*)&Vs[d * 1024 + c0 + m4];
    }
    __syncthreads();
    float4 s[4] = {};
#pragma unroll
    for (int d = 0; d < 16; ++d) {
      const float4 kk = *(const float4*)&Kc[d][lane << 2];
#pragma unroll
      for (int r = 0; r < 4; ++r) {
        s[r].x += qr[r][d] * kk.x; s[r].y += qr[r][d] * kk.y;
        s[r].z += qr[r][d] * kk.z; s[r].w += qr[r][d] * kk.w;
      }
    }
    float4 p[4];
#pragma unroll
    for (int r = 0; r < 4; ++r) {
      p[r].x = exp2f(s[r].x * sc); p[r].y = exp2f(s[r].y * sc);
      p[r].z = exp2f(s[r].z * sc); p[r].w = exp2f(s[r].w * sc);
      l[r] += p[r].x + p[r].y + p[r].z + p[r].w;
    }
#pragma unroll
    for (int d = 0; d < 16; ++d) {
      const float4 vv = *(const float4*)&Vc[d][lane << 2];
#pragma unroll
      for (int r = 0; r < 4; ++r) {
        o[r][d] += p[r].x * vv.x + p[r].y * vv.y + p[r].z * vv.z +
                   p[r].w * vv.w;
      }
    }
  }
#pragma unroll
  for (int r = 0; r < 4; ++r) {
    float lv = l[r];
    for (int m = 1; m < 64; m <<= 1) lv += __shfl_xor(lv, m, 64);
    l[r] = 1.0f / lv;
  }
  const int qd = lane >> 4;
  const int dd = lane & 15;
#pragma unroll
  for (int r = 0; r < 4; ++r) {
    __syncthreads();
#pragma unroll
    for (int i = 0; i < 4; ++i)
      *(float4*)&red[w][lane][i << 2] =
          make_float4(o[r][(i << 2) + 0], o[r][(i << 2) + 1],
                      o[r][(i << 2) + 2], o[r][(i << 2) + 3]);
    __syncthreads();
    float part = 0.f;
#pragma unroll
    for (int i = 0; i < 16; ++i) part += red[w][(qd << 4) + i][dd];
    part += __shfl_xor(part, 16, 64);
    part += __shfl_xor(part, 32, 64);
    if (lane < 16)
      out2[((b << 10) + row0 + r) * DIM + (h << 4) + dd] = part * l[r];
  }
}

// ---------------------------------------------------------------------------
// Final linear: y[m][o] = sum_c inp[m][c] * wpT[c][o].
// Output dtype selected at runtime by the detected input dtype (dataset is
// dtype-consistent): bf16 (RNE) when inputs bf16, fp32 otherwise.
// ---------------------------------------------------------------------------
__device__ inline unsigned short f2bf(float f) {
  union { float f; unsigned u; } v;
  v.f = f;
  unsigned u = v.u;
  u += 0x7fffu + ((u >> 16) & 1u);
  return (unsigned short)(u >> 16);
}

__global__ __launch_bounds__(256) void linear_kernel(
    const float* __restrict__ inp,   // [8192][256]
    const float* __restrict__ wpT,   // [256 ci][256 co]
    void* __restrict__ out, const int* __restrict__ flag) {
  __shared__ float As[16][64];
  __shared__ float Bs[16][64];
  const int isf32 = *flag;
  const int t   = threadIdx.x;
  const int m0  = blockIdx.x << 6;
  const int co0 = blockIdx.y << 6;
  const int tx = t & 15, ty = t >> 4;
  const int pA = t >> 2, cgA = (t & 3) << 2;
  const int ciB = t >> 4, co4B = (t & 15) << 2;
  float acc[4][4] = {{0.f, 0.f, 0.f, 0.f}};
  for (int c0 = 0; c0 < DIM; c0 += 16) {
    const float4 av = *(const float4*)&inp[(m0 + pA) * DIM + c0 + cgA];
    const float4 bv = *(const float4*)&wpT[(c0 + ciB) * DIM + co0 + co4B];
    __syncthreads();
    As[cgA + 0][pA] = av.x;
    As[cgA + 1][pA] = av.y;
    As[cgA + 2][pA] = av.z;
    As[cgA + 3][pA] = av.w;
    *(float4*)&Bs[ciB][co4B] = bv;
    __syncthreads();
#pragma unroll
    for (int kk = 0; kk < 16; ++kk) {
      const float4 a  = *(const float4*)&As[kk][tx << 2];
      const float4 bb = *(const float4*)&Bs[kk][ty << 2];
      acc[0][0] += a.x * bb.x; acc[0][1] += a.x * bb.y;
      acc[0][2] += a.x * bb.z; acc[0][3] += a.x * bb.w;
      acc[1][0] += a.y * bb.x; acc[1][1] += a.y * bb.y;
      acc[1][2] += a.y * bb.z; acc[1][3] += a.y * bb.w;
      acc[2][0] += a.z * bb.x; acc[2][1] += a.z * bb.y;
      acc[2][2] += a.z * bb.z; acc[2][3] += a.z * bb.w;
      acc[3][0] += a.w * bb.x; acc[3][1] += a.w * bb.y;
      acc[3][2] += a.w * bb.z; acc[3][3] += a.w * bb.w;
    }
  }
  const int row = m0 + (tx << 2);
  if (!isf32) {
    unsigned short* o16 = (unsigned short*)out;
#pragma unroll
    for (int i = 0; i < 4; ++i) {
      ushort4 sv;
      sv.x = f2bf(acc[i][0]); sv.y = f2bf(acc[i][1]);
      sv.z = f2bf(acc[i][2]); sv.w = f2bf(acc[i][3]);
      *(ushort4*)&o16[(row + i) * DIM + co0 + (ty << 2)] = sv;
    }
  } else {
    float* o32 = (float*)out;
#pragma unroll
    for (int i = 0; i < 4; ++i) {
      *(float4*)&o32[(row + i) * DIM + co0 + (ty << 2)] =
          make_float4(acc[i][0], acc[i][1], acc[i][2], acc[i][3]);
    }
  }
}

// ---------------------------------------------------------------------------
extern "C" void kernel_launch(void* const* d_in, const int* in_sizes, int n_in,
                              void* d_out, int out_size, void* d_ws,
                              size_t ws_size, hipStream_t stream) {
  const void* x  = d_in[0];
  const void* w3 = d_in[1];
  const void* b3 = d_in[2];
  const void* w5 = d_in[3];
  const void* b5 = d_in[4];
  const void* w7 = d_in[5];
  const void* b7 = d_in[6];
  const void* wp = d_in[7];

  float* ws  = (float*)d_ws;
  int*   flag = (int*)ws;            // 16 floats reserved
  float* xc  = ws + 16;              // 2097152  x canonical fp32 (NHWC)
  float* qc  = xc + 2097152;         // 2097152  q, NCHW
  float* kTt = qc + 2097152;         // 2097152  k, slab-transposed [d][m]
  float* vTt = kTt + 2097152;        // 2097152  v, slab-transposed [d][m]
  float* o2  = vTt + 2097152;        // 2097152  attention out, [B][N][256]
  float* wT3 = o2 + 2097152;         // 65536
  float* wT5 = wT3 + 65536;          // 589824
  float* wT7 = wT5 + 589824;         // 1638400
  float* wpT = wT7 + 1638400;        // 65536
  float* b3c = wpT + 65536;          // 256
  float* b5c = b3c + 256;            // 256
  float* b7c = b5c + 256;            // 256   (total ~51.5 MB)

  detect_kernel<<<1, 256, 0, stream>>>((const unsigned short*)x, flag);

  convert_kernel<<<8192, 256, 0, stream>>>(x, xc, 2097152, flag);
  convert_kernel<<<1, 256, 0, stream>>>(b3, b3c, 256, flag);
  convert_kernel<<<1, 256, 0, stream>>>(b5, b5c, 256, flag);
  convert_kernel<<<1, 256, 0, stream>>>(b7, b7c, 256, flag);

  wtrans_kernel<<<256, 256, 0, stream>>>(w3, wT3, 1, flag);
  wtrans_kernel<<<2304, 256, 0, stream>>>(w5, wT5, 9, flag);
  wtrans_kernel<<<6400, 256, 0, stream>>>(w7, wT7, 25, flag);
  wtrans_kernel<<<256, 256, 0, stream>>>(wp, wpT, 1, flag);

  dim3 cg(128, 4);
  conv_kernel<1, 0><<<cg, 256, 0, stream>>>(xc, wT3, b3c, qc);   // q : 1x1
  conv_kernel<3, 1><<<cg, 256, 0, stream>>>(xc, wT5, b5c, vTt);  // v : 3x3
  conv_kernel<5, 1><<<cg, 256, 0, stream>>>(xc, wT7, b7c, kTt);  // k : 5x5

  attn_kernel<<<8192, 256, 0, stream>>>(qc, kTt, vTt, o2);

  dim3 lg(128, 4);
  linear_kernel<<<lg, 256, 0, stream>>>(o2, wpT, d_out, flag);
}

// Round 3
// 603.774 us; speedup vs baseline: 1.7012x; 1.7012x over previous
//
#include <hip/hip_runtime.h>
#include <hip/hip_bf16.h>

#define DIM 256
#define HW  1024  // 32*32

typedef __attribute__((ext_vector_type(8))) short short8;
typedef __attribute__((ext_vector_type(4))) float floatx4;

__device__ inline unsigned short f2bf(float f) {
  union { float f; unsigned u; } v;
  v.f = f;
  unsigned u = v.u;
  u += 0x7fffu + ((u >> 16) & 1u);
  return (unsigned short)(u >> 16);
}

// ---------------------------------------------------------------------------
// Dtype detector: flag=1 if inputs are fp32, 0 if bf16 (see R2 notes).
// ---------------------------------------------------------------------------
__global__ void detect_kernel(const unsigned short* __restrict__ xr,
                              int* __restrict__ flag) {
  __shared__ int cnt;
  if (threadIdx.x == 0) cnt = 0;
  __syncthreads();
  int local = 0;
  for (int i = threadIdx.x; i < 8192; i += 256) {
    unsigned short u = xr[i];
    if ((u & 0x7F80u) == 0x7F80u) local++;
  }
  if (local) atomicAdd(&cnt, local);
  __syncthreads();
  if (threadIdx.x == 0) *flag = (cnt > 0) ? 1 : 0;
}

__device__ inline float ldin(const void* p, long i, int isf32) {
  if (isf32) return ((const float*)p)[i];
  union { unsigned u; float f; } v;
  v.u = ((unsigned)((const unsigned short*)p)[i]) << 16;
  return v.f;
}

// Generic element converter -> fp32 (biases)
__global__ void convert_kernel(const void* __restrict__ src,
                               float* __restrict__ dst, int n,
                               const int* __restrict__ flag) {
  const int isf32 = *flag;
  int i = blockIdx.x * 256 + threadIdx.x;
  if (i < n) dst[i] = ldin(src, i, isf32);
}

// x -> canonical bf16 (ushort), 4 elem/thread
__global__ void xconv_kernel(const void* __restrict__ src,
                             unsigned short* __restrict__ dst,
                             const int* __restrict__ flag) {
  const int isf32 = *flag;
  const int i = (blockIdx.x * 256 + threadIdx.x) * 4;
  if (isf32) {
    const float4 v = *(const float4*)((const float*)src + i);
    ushort4 o;
    o.x = f2bf(v.x); o.y = f2bf(v.y); o.z = f2bf(v.z); o.w = f2bf(v.w);
    *(ushort4*)(dst + i) = o;
  } else {
    *(ushort4*)(dst + i) = *(const ushort4*)((const unsigned short*)src + i);
  }
}

// Conv weights OIHW [co][ci][KK] -> bf16 [tap][co][ci]
__global__ void wbconv_kernel(const void* __restrict__ w,
                              unsigned short* __restrict__ wB, int KK,
                              const int* __restrict__ flag) {
  const int isf32 = *flag;
  int idx = blockIdx.x * 256 + threadIdx.x;
  int total = 65536 * KK;
  if (idx >= total) return;
  int ci = idx & 255;
  int co = (idx >> 8) & 255;
  int tap = idx >> 16;
  wB[idx] = f2bf(ldin(w, (long)(co * 256 + ci) * KK + tap, isf32));
}

// wp [o][i] -> wpT fp32 [i][o]
__global__ void wtrans_kernel(const void* __restrict__ w,
                              float* __restrict__ wT,
                              const int* __restrict__ flag) {
  const int isf32 = *flag;
  int idx = blockIdx.x * 256 + threadIdx.x;
  int co = idx & 255;
  int ci = idx >> 8;
  wT[idx] = ldin(w, (long)(co * 256 + ci), isf32);
}

// ---------------------------------------------------------------------------
// MFMA implicit-GEMM conv, SAME padding, stride 1, bf16 in / fp32 out.
//   xbf : [8][32][32][256] bf16 NHWC
//   wB  : [KS*KS][co=256][ci=256] bf16
//   out : TSTORE==0 -> NCHW [B][256][1024]   (q)
//         TSTORE==1 -> slab layout (k, v):
//                      out[(b*16+(co>>4))*16384 + (n&15)*1024 + (co&15)*64 + (n>>4)]
// Block: 256 thr = 4 waves; tile 64 pos x 64 co; wave = 32x32 (2x2 MFMA frags).
// Grid: (128, 4) = 512 blocks -> 2 blocks/CU.
// ---------------------------------------------------------------------------
template <int KS, int TSTORE>
__global__ __launch_bounds__(256) void conv_mfma_kernel(
    const unsigned short* __restrict__ xbf,
    const unsigned short* __restrict__ wB,
    const float* __restrict__ bias, float* __restrict__ out) {
  constexpr int P = KS / 2;
  __shared__ unsigned short As[64][40];  // [pos][ci] pad->80B rows (2-way=free)
  __shared__ unsigned short Bs[64][40];  // [co][ci]
  const int t   = threadIdx.x;
  const int m0  = blockIdx.x << 6;   // 64 positions / block
  const int b   = m0 >> 10;
  const int n0  = m0 & 1023;         // multiple of 64 -> 2 image rows
  const int r0  = n0 >> 5;
  const int co0 = blockIdx.y << 6;
  const int wv   = t >> 6;
  const int lane = t & 63;
  const int wm = (wv & 1) << 5;      // wave m-offset: 0/32
  const int wn = (wv >> 1) << 5;     // wave n-offset: 0/32
  const int l15  = lane & 15;
  const int quad = lane >> 4;
  // staging: thread -> (row = t>>2, ci-off = (t&3)*8), 16B each for A and B
  const int posA = t >> 2;
  const int cioA = (t & 3) << 3;
  const int rowA = r0 + (posA >> 5);
  const int colA = posA & 31;

  floatx4 acc[2][2] = {};

  for (int kh = 0; kh < KS; ++kh) {
    const int hx = rowA + kh - P;
    for (int kw = 0; kw < KS; ++kw) {
      const int wx = colA + kw - P;
      const bool ok = ((unsigned)hx < 32u) && ((unsigned)wx < 32u);
      const unsigned short* xb =
          xbf + ((((b * 32 + hx) * 32 + wx) << 8) + cioA);
      const unsigned short* wb =
          wB + (((((kh * KS + kw) << 8) + co0 + posA) << 8) + cioA);
      for (int ci0 = 0; ci0 < 256; ci0 += 32) {
        uint4 av = make_uint4(0, 0, 0, 0);
        if (ok) av = *(const uint4*)(xb + ci0);
        const uint4 bv = *(const uint4*)(wb + ci0);
        __syncthreads();  // previous chunk's LDS reads done
        *(uint4*)&As[posA][cioA] = av;
        *(uint4*)&Bs[posA][cioA] = bv;
        __syncthreads();
        short8 afr0 = *(const short8*)&As[wm + l15][quad << 3];
        short8 afr1 = *(const short8*)&As[wm + 16 + l15][quad << 3];
        short8 bfr0 = *(const short8*)&Bs[wn + l15][quad << 3];
        short8 bfr1 = *(const short8*)&Bs[wn + 16 + l15][quad << 3];
        acc[0][0] = __builtin_amdgcn_mfma_f32_16x16x32_bf16(afr0, bfr0,
                                                            acc[0][0], 0, 0, 0);
        acc[0][1] = __builtin_amdgcn_mfma_f32_16x16x32_bf16(afr0, bfr1,
                                                            acc[0][1], 0, 0, 0);
        acc[1][0] = __builtin_amdgcn_mfma_f32_16x16x32_bf16(afr1, bfr0,
                                                            acc[1][0], 0, 0, 0);
        acc[1][1] = __builtin_amdgcn_mfma_f32_16x16x32_bf16(afr1, bfr1,
                                                            acc[1][1], 0, 0, 0);
      }
    }
  }
  // epilogue: D row = quad*4+reg, col = l15 (m89-verified C/D layout)
#pragma unroll
  for (int mi = 0; mi < 2; ++mi) {
#pragma unroll
    for (int ni = 0; ni < 2; ++ni) {
      const int co = co0 + wn + (ni << 4) + l15;
      const float bj = bias[co];
      const int nb = n0 + wm + (mi << 4) + (quad << 2);
      floatx4 a = acc[mi][ni];
      if (TSTORE == 0) {
        *(float4*)&out[(((b << 8) + co) << 10) + nb] =
            make_float4(a[0] + bj, a[1] + bj, a[2] + bj, a[3] + bj);
      } else {
        const int base = (((b << 4) + (co >> 4)) << 14) + ((co & 15) << 6);
#pragma unroll
        for (int i = 0; i < 4; ++i) {
          const int n = nb + i;
          out[base + ((n & 15) << 10) + (n >> 4)] = a[i] + bj;
        }
      }
    }
  }
}

// ---------------------------------------------------------------------------
// Attention per (b,h) slab: softmax(Q K^T * 0.25) V.  (unchanged, passed R2)
// ---------------------------------------------------------------------------
__global__ __launch_bounds__(256) void attn_kernel(
    const float* __restrict__ q, const float* __restrict__ kT,
    const float* __restrict__ vT, float* __restrict__ out2) {
  __shared__ float Kc[16][256];
  __shared__ float Vc[16][256];
  __shared__ float red[4][64][20];
  const int t    = threadIdx.x;
  const int w    = t >> 6;
  const int lane = t & 63;
  const int slab = blockIdx.x >> 6;
  const int rb   = blockIdx.x & 63;
  const int b = slab >> 4;
  const int h = slab & 15;
  const float* Qs = q  + slab * 16384;
  const float* Ks = kT + slab * 16384;
  const float* Vs = vT + slab * 16384;
  const int row0 = (rb << 4) + (w << 2);

  float qr[4][16];
#pragma unroll
  for (int r = 0; r < 4; ++r) {
#pragma unroll
    for (int d4 = 0; d4 < 16; d4 += 4) {
      const float4 qv = *(const float4*)&Qs[(row0 + r) * 16 + d4];
      qr[r][d4 + 0] = qv.x; qr[r][d4 + 1] = qv.y;
      qr[r][d4 + 2] = qv.z; qr[r][d4 + 3] = qv.w;
    }
  }
  float o[4][16] = {};
  float l[4] = {0.f, 0.f, 0.f, 0.f};
  const float sc = 0.25f * 1.4426950408889634f;

  for (int c0 = 0; c0 < 1024; c0 += 256) {
    __syncthreads();
#pragma unroll
    for (int i = 0; i < 4; ++i) {
      const int f  = (i << 8) + t;
      const int d  = f >> 6;
      const int m4 = (f & 63) << 2;
      *(float4*)&Kc[d][m4] = *(const float4*)&Ks[d * 1024 + c0 + m4];
      *(float4*)&Vc[d][m4] = *(const float4*)&Vs[d * 1024 + c0 + m4];
    }
    __syncthreads();
    float4 s[4] = {};
#pragma unroll
    for (int d = 0; d < 16; ++d) {
      const float4 kk = *(const float4*)&Kc[d][lane << 2];
#pragma unroll
      for (int r = 0; r < 4; ++r) {
        s[r].x += qr[r][d] * kk.x; s[r].y += qr[r][d] * kk.y;
        s[r].z += qr[r][d] * kk.z; s[r].w += qr[r][d] * kk.w;
      }
    }
    float4 p[4];
#pragma unroll
    for (int r = 0; r < 4; ++r) {
      p[r].x = exp2f(s[r].x * sc); p[r].y = exp2f(s[r].y * sc);
      p[r].z = exp2f(s[r].z * sc); p[r].w = exp2f(s[r].w * sc);
      l[r] += p[r].x + p[r].y + p[r].z + p[r].w;
    }
#pragma unroll
    for (int d = 0; d < 16; ++d) {
      const float4 vv = *(const float4*)&Vc[d][lane << 2];
#pragma unroll
      for (int r = 0; r < 4; ++r) {
        o[r][d] += p[r].x * vv.x + p[r].y * vv.y + p[r].z * vv.z +
                   p[r].w * vv.w;
      }
    }
  }
#pragma unroll
  for (int r = 0; r < 4; ++r) {
    float lv = l[r];
    for (int m = 1; m < 64; m <<= 1) lv += __shfl_xor(lv, m, 64);
    l[r] = 1.0f / lv;
  }
  const int qd = lane >> 4;
  const int dd = lane & 15;
#pragma unroll
  for (int r = 0; r < 4; ++r) {
    __syncthreads();
#pragma unroll
    for (int i = 0; i < 4; ++i)
      *(float4*)&red[w][lane][i << 2] =
          make_float4(o[r][(i << 2) + 0], o[r][(i << 2) + 1],
                      o[r][(i << 2) + 2], o[r][(i << 2) + 3]);
    __syncthreads();
    float part = 0.f;
#pragma unroll
    for (int i = 0; i < 16; ++i) part += red[w][(qd << 4) + i][dd];
    part += __shfl_xor(part, 16, 64);
    part += __shfl_xor(part, 32, 64);
    if (lane < 16)
      out2[((b << 10) + row0 + r) * DIM + (h << 4) + dd] = part * l[r];
  }
}

// ---------------------------------------------------------------------------
// Final linear (unchanged, passed R2).
// ---------------------------------------------------------------------------
__global__ __launch_bounds__(256) void linear_kernel(
    const float* __restrict__ inp, const float* __restrict__ wpT,
    void* __restrict__ out, const int* __restrict__ flag) {
  __shared__ float As[16][64];
  __shared__ float Bs[16][64];
  const int isf32 = *flag;
  const int t   = threadIdx.x;
  const int m0  = blockIdx.x << 6;
  const int co0 = blockIdx.y << 6;
  const int tx = t & 15, ty = t >> 4;
  const int pA = t >> 2, cgA = (t & 3) << 2;
  const int ciB = t >> 4, co4B = (t & 15) << 2;
  float acc[4][4] = {{0.f, 0.f, 0.f, 0.f}};
  for (int c0 = 0; c0 < DIM; c0 += 16) {
    const float4 av = *(const float4*)&inp[(m0 + pA) * DIM + c0 + cgA];
    const float4 bv = *(const float4*)&wpT[(c0 + ciB) * DIM + co0 + co4B];
    __syncthreads();
    As[cgA + 0][pA] = av.x;
    As[cgA + 1][pA] = av.y;
    As[cgA + 2][pA] = av.z;
    As[cgA + 3][pA] = av.w;
    *(float4*)&Bs[ciB][co4B] = bv;
    __syncthreads();
#pragma unroll
    for (int kk = 0; kk < 16; ++kk) {
      const float4 a  = *(const float4*)&As[kk][tx << 2];
      const float4 bb = *(const float4*)&Bs[kk][ty << 2];
      acc[0][0] += a.x * bb.x; acc[0][1] += a.x * bb.y;
      acc[0][2] += a.x * bb.z; acc[0][3] += a.x * bb.w;
      acc[1][0] += a.y * bb.x; acc[1][1] += a.y * bb.y;
      acc[1][2] += a.y * bb.z; acc[1][3] += a.y * bb.w;
      acc[2][0] += a.z * bb.x; acc[2][1] += a.z * bb.y;
      acc[2][2] += a.z * bb.z; acc[2][3] += a.z * bb.w;
      acc[3][0] += a.w * bb.x; acc[3][1] += a.w * bb.y;
      acc[3][2] += a.w * bb.z; acc[3][3] += a.w * bb.w;
    }
  }
  const int row = m0 + (tx << 2);
  if (!isf32) {
    unsigned short* o16 = (unsigned short*)out;
#pragma unroll
    for (int i = 0; i < 4; ++i) {
      ushort4 sv;
      sv.x = f2bf(acc[i][0]); sv.y = f2bf(acc[i][1]);
      sv.z = f2bf(acc[i][2]); sv.w = f2bf(acc[i][3]);
      *(ushort4*)&o16[(row + i) * DIM + co0 + (ty << 2)] = sv;
    }
  } else {
    float* o32 = (float*)out;
#pragma unroll
    for (int i = 0; i < 4; ++i) {
      *(float4*)&o32[(row + i) * DIM + co0 + (ty << 2)] =
          make_float4(acc[i][0], acc[i][1], acc[i][2], acc[i][3]);
    }
  }
}

// ---------------------------------------------------------------------------
extern "C" void kernel_launch(void* const* d_in, const int* in_sizes, int n_in,
                              void* d_out, int out_size, void* d_ws,
                              size_t ws_size, hipStream_t stream) {
  const void* x  = d_in[0];
  const void* w3 = d_in[1];
  const void* b3 = d_in[2];
  const void* w5 = d_in[3];
  const void* b5 = d_in[4];
  const void* w7 = d_in[5];
  const void* b7 = d_in[6];
  const void* wp = d_in[7];

  char* p = (char*)d_ws;
  int* flag = (int*)p;                       p += 256;
  unsigned short* xbf = (unsigned short*)p;  p += 4u * 1024 * 1024;
  unsigned short* wB3 = (unsigned short*)p;  p += 131072;
  unsigned short* wB5 = (unsigned short*)p;  p += 1179648;
  unsigned short* wB7 = (unsigned short*)p;  p += 3276800;
  float* wpT = (float*)p;                    p += 262144;
  float* b3c = (float*)p;                    p += 1024;
  float* b5c = (float*)p;                    p += 1024;
  float* b7c = (float*)p;                    p += 1024;
  float* qc  = (float*)p;                    p += 8388608;
  float* kT  = (float*)p;                    p += 8388608;
  float* vT  = (float*)p;                    p += 8388608;
  float* o2  = (float*)p;                    p += 8388608;

  detect_kernel<<<1, 256, 0, stream>>>((const unsigned short*)x, flag);

  xconv_kernel<<<2048, 256, 0, stream>>>(x, xbf, flag);
  wbconv_kernel<<<256, 256, 0, stream>>>(w3, wB3, 1, flag);
  wbconv_kernel<<<2304, 256, 0, stream>>>(w5, wB5, 9, flag);
  wbconv_kernel<<<6400, 256, 0, stream>>>(w7, wB7, 25, flag);
  wtrans_kernel<<<256, 256, 0, stream>>>(wp, wpT, flag);
  convert_kernel<<<1, 256, 0, stream>>>(b3, b3c, 256, flag);
  convert_kernel<<<1, 256, 0, stream>>>(b5, b5c, 256, flag);
  convert_kernel<<<1, 256, 0, stream>>>(b7, b7c, 256, flag);

  dim3 cg(128, 4);
  conv_mfma_kernel<1, 0><<<cg, 256, 0, stream>>>(xbf, wB3, b3c, qc);  // q
  conv_mfma_kernel<3, 1><<<cg, 256, 0, stream>>>(xbf, wB5, b5c, vT);  // v
  conv_mfma_kernel<5, 1><<<cg, 256, 0, stream>>>(xbf, wB7, b7c, kT);  // k

  attn_kernel<<<8192, 256, 0, stream>>>(qc, kT, vT, o2);

  dim3 lg(128, 4);
  linear_kernel<<<lg, 256, 0, stream>>>(o2, wpT, d_out, flag);
}

// Round 5
// 308.441 us; speedup vs baseline: 3.3302x; 1.9575x over previous
//
#include <hip/hip_runtime.h>
#include <hip/hip_bf16.h>

#define DIM 256
#define HW  1024  // 32*32

typedef __attribute__((ext_vector_type(8))) short short8;
typedef __attribute__((ext_vector_type(4))) float floatx4;
typedef __attribute__((ext_vector_type(16))) float floatx16;

__device__ inline unsigned short f2bf(float f) {
  union { float f; unsigned u; } v;
  v.f = f;
  unsigned u = v.u;
  u += 0x7fffu + ((u >> 16) & 1u);
  return (unsigned short)(u >> 16);
}

// ---------------------------------------------------------------------------
// Dtype detector: flag=1 if inputs are fp32, 0 if bf16 (see R2 notes).
// ---------------------------------------------------------------------------
__global__ void detect_kernel(const unsigned short* __restrict__ xr,
                              int* __restrict__ flag) {
  __shared__ int cnt;
  if (threadIdx.x == 0) cnt = 0;
  __syncthreads();
  int local = 0;
  for (int i = threadIdx.x; i < 8192; i += 256) {
    unsigned short u = xr[i];
    if ((u & 0x7F80u) == 0x7F80u) local++;
  }
  if (local) atomicAdd(&cnt, local);
  __syncthreads();
  if (threadIdx.x == 0) *flag = (cnt > 0) ? 1 : 0;
}

__device__ inline float ldin(const void* p, long i, int isf32) {
  if (isf32) return ((const float*)p)[i];
  union { unsigned u; float f; } v;
  v.u = ((unsigned)((const unsigned short*)p)[i]) << 16;
  return v.f;
}

// Generic element converter -> fp32 (biases)
__global__ void convert_kernel(const void* __restrict__ src,
                               float* __restrict__ dst, int n,
                               const int* __restrict__ flag) {
  const int isf32 = *flag;
  int i = blockIdx.x * 256 + threadIdx.x;
  if (i < n) dst[i] = ldin(src, i, isf32);
}

// x -> canonical bf16 (ushort), 4 elem/thread
__global__ void xconv_kernel(const void* __restrict__ src,
                             unsigned short* __restrict__ dst,
                             const int* __restrict__ flag) {
  const int isf32 = *flag;
  const int i = (blockIdx.x * 256 + threadIdx.x) * 4;
  if (isf32) {
    const float4 v = *(const float4*)((const float*)src + i);
    ushort4 o;
    o.x = f2bf(v.x); o.y = f2bf(v.y); o.z = f2bf(v.z); o.w = f2bf(v.w);
    *(ushort4*)(dst + i) = o;
  } else {
    *(ushort4*)(dst + i) = *(const ushort4*)((const unsigned short*)src + i);
  }
}

// Conv weights OIHW [co][ci][KK] -> bf16 [tap][co][ci]
__global__ void wbconv_kernel(const void* __restrict__ w,
                              unsigned short* __restrict__ wB, int KK,
                              const int* __restrict__ flag) {
  const int isf32 = *flag;
  int idx = blockIdx.x * 256 + threadIdx.x;
  int total = 65536 * KK;
  if (idx >= total) return;
  int ci = idx & 255;
  int co = (idx >> 8) & 255;
  int tap = idx >> 16;
  wB[idx] = f2bf(ldin(w, (long)(co * 256 + ci) * KK + tap, isf32));
}

// wp [o][i] -> wpT fp32 [i][o]
__global__ void wtrans_kernel(const void* __restrict__ w,
                              float* __restrict__ wT,
                              const int* __restrict__ flag) {
  const int isf32 = *flag;
  int idx = blockIdx.x * 256 + threadIdx.x;
  int co = idx & 255;
  int ci = idx >> 8;
  wT[idx] = ldin(w, (long)(co * 256 + ci), isf32);
}

// ---------------------------------------------------------------------------
// MFMA implicit-GEMM conv, SAME padding, stride 1, bf16 in / bf16 out.
//   xbf : [8][32][32][256] bf16 NHWC
//   wB  : [KS*KS][co=256][ci=256] bf16
// Attention coords (reshape algebra, R2-verified): slab=(b<<4)+(co>>4),
//   m = (co&15)*64 + (n>>4), d = n&15   [m*16+d == (co&15)*1024 + n]
//   out : TSTORE==0 -> QK row layout bf16 [slab][m][16 d]:
//                      out[(slab<<14) + ((co&15)<<10) + n]       (contig in n)
//         TSTORE==1 -> V^T layout bf16 [slab][d][1024 m]:
//                      out[(slab<<14) + ((n&15)<<10) + ((co&15)<<6) + (n>>4)]
// Block: 256 thr = 4 waves; tile 64 pos x 64 co; wave = 32x32 (2x2 MFMA frags).
// ---------------------------------------------------------------------------
template <int KS, int TSTORE>
__global__ __launch_bounds__(256) void conv_mfma_kernel(
    const unsigned short* __restrict__ xbf,
    const unsigned short* __restrict__ wB,
    const float* __restrict__ bias, unsigned short* __restrict__ out) {
  constexpr int P = KS / 2;
  __shared__ unsigned short As[64][40];  // [pos][ci] pad->80B rows
  __shared__ unsigned short Bs[64][40];  // [co][ci]
  const int t   = threadIdx.x;
  const int m0  = blockIdx.x << 6;
  const int b   = m0 >> 10;
  const int n0  = m0 & 1023;
  const int r0  = n0 >> 5;
  const int co0 = blockIdx.y << 6;
  const int wv   = t >> 6;
  const int lane = t & 63;
  const int wm = (wv & 1) << 5;
  const int wn = (wv >> 1) << 5;
  const int l15  = lane & 15;
  const int quad = lane >> 4;
  const int posA = t >> 2;
  const int cioA = (t & 3) << 3;
  const int rowA = r0 + (posA >> 5);
  const int colA = posA & 31;

  floatx4 acc[2][2] = {};

  for (int kh = 0; kh < KS; ++kh) {
    const int hx = rowA + kh - P;
    for (int kw = 0; kw < KS; ++kw) {
      const int wx = colA + kw - P;
      const bool ok = ((unsigned)hx < 32u) && ((unsigned)wx < 32u);
      const unsigned short* xb =
          xbf + ((((b * 32 + hx) * 32 + wx) << 8) + cioA);
      const unsigned short* wb =
          wB + (((((kh * KS + kw) << 8) + co0 + posA) << 8) + cioA);
      for (int ci0 = 0; ci0 < 256; ci0 += 32) {
        uint4 av = make_uint4(0, 0, 0, 0);
        if (ok) av = *(const uint4*)(xb + ci0);
        const uint4 bv = *(const uint4*)(wb + ci0);
        __syncthreads();
        *(uint4*)&As[posA][cioA] = av;
        *(uint4*)&Bs[posA][cioA] = bv;
        __syncthreads();
        short8 afr0 = *(const short8*)&As[wm + l15][quad << 3];
        short8 afr1 = *(const short8*)&As[wm + 16 + l15][quad << 3];
        short8 bfr0 = *(const short8*)&Bs[wn + l15][quad << 3];
        short8 bfr1 = *(const short8*)&Bs[wn + 16 + l15][quad << 3];
        acc[0][0] = __builtin_amdgcn_mfma_f32_16x16x32_bf16(afr0, bfr0,
                                                            acc[0][0], 0, 0, 0);
        acc[0][1] = __builtin_amdgcn_mfma_f32_16x16x32_bf16(afr0, bfr1,
                                                            acc[0][1], 0, 0, 0);
        acc[1][0] = __builtin_amdgcn_mfma_f32_16x16x32_bf16(afr1, bfr0,
                                                            acc[1][0], 0, 0, 0);
        acc[1][1] = __builtin_amdgcn_mfma_f32_16x16x32_bf16(afr1, bfr1,
                                                            acc[1][1], 0, 0, 0);
      }
    }
  }
  // epilogue: C/D layout col=l15 (co), row=quad*4+reg (position)
#pragma unroll
  for (int mi = 0; mi < 2; ++mi) {
#pragma unroll
    for (int ni = 0; ni < 2; ++ni) {
      const int co = co0 + wn + (ni << 4) + l15;
      const float bj = bias[co];
      const int nb = n0 + wm + (mi << 4) + (quad << 2);
      const int slab = (b << 4) + (co >> 4);
      const int clo = co & 15;
      floatx4 a = acc[mi][ni];
      if (TSTORE == 0) {
        // [slab][m][d] contiguous: (slab<<14) + clo*1024 + n, 4 contig n
        ushort4 pk;
        pk.x = f2bf(a[0] + bj); pk.y = f2bf(a[1] + bj);
        pk.z = f2bf(a[2] + bj); pk.w = f2bf(a[3] + bj);
        *(ushort4*)&out[(slab << 14) + (clo << 10) + nb] = pk;
      } else {
        // V^T [slab][d=n&15][m=clo*64+(n>>4)]
        const int base = (slab << 14) + (clo << 6);
#pragma unroll
        for (int i = 0; i < 4; ++i) {
          const int n = nb + i;
          out[base + ((n & 15) << 10) + (n >> 4)] = f2bf(a[i] + bj);
        }
      }
    }
  }
}

// ---------------------------------------------------------------------------
// MFMA attention per (b,h) slab: softmax(Q K^T * 0.25) V.
//   qg, kg : bf16 [slab][1024 m][16 d]  (QK row layout)
//   vg     : bf16 [slab][16 d][1024 m]  (V^T layout)
//   out2   : fp32 [8][1024 m][256], c = h*16+d
// Block = 4 waves x 32 q-rows = 128 rows; grid = 128 slabs x 8 row-blocks.
// QK^T: one 32x32x16 MFMA per 32-key chunk; P via per-wave LDS buffer
// (wave-internal LDS ordering, no barrier); PV: 2x 16x16x32 MFMA.
// No max-subtraction (|logit*scale| << 88).
// ---------------------------------------------------------------------------
__global__ __launch_bounds__(256) void attn_mfma_kernel(
    const unsigned short* __restrict__ qg,
    const unsigned short* __restrict__ kg,
    const unsigned short* __restrict__ vg,
    float* __restrict__ out2) {
  __shared__ __align__(16) unsigned short Kc[16384];     // [key][16]
  __shared__ __align__(16) unsigned short Vt[16][1032];  // [d][key], padded
  __shared__ __align__(16) unsigned short Pb[4][32][40]; // per-wave P
  __shared__ float lb[4][32];
  const int t    = threadIdx.x;
  const int w    = t >> 6;
  const int lane = t & 63;
  const int slab = blockIdx.x >> 3;
  const int rb   = blockIdx.x & 7;
  const int b = slab >> 4;
  const int h = slab & 15;
  const int l31  = lane & 31;
  const int hl   = lane >> 5;
  const int l15  = lane & 15;
  const int quad = lane >> 4;

  // stage K rows and V^T into LDS
#pragma unroll
  for (int j = 0; j < 8; ++j) {
    const int id = (j << 8) + t;   // 0..2047
    const int e  = id << 3;        // element idx (x8 bf16)
    *(uint4*)&Kc[e] = *(const uint4*)&kg[(slab << 14) + e];
    const int d = e >> 10, ky = e & 1023;
    *(uint4*)&Vt[d][ky] = *(const uint4*)&vg[(slab << 14) + e];
  }

  const int row0 = (rb << 7) + (w << 5);  // wave's first q-row
  const short8 qa =
      *(const short8*)&qg[(slab << 14) + ((row0 + l31) << 4) + (hl << 3)];

  float lsum[16] = {};
  floatx4 acco[2] = {};
  const float sc = 0.25f * 1.4426950408889634f;

  __syncthreads();

  for (int kc = 0; kc < 1024; kc += 32) {
    const short8 kb = *(const short8*)&Kc[((kc + l31) << 4) + (hl << 3)];
    floatx16 s = {};
    s = __builtin_amdgcn_mfma_f32_32x32x16_bf16(qa, kb, s, 0, 0, 0);
    // exp2, accumulate row sums, stash P (bf16) in per-wave LDS
#pragma unroll
    for (int r = 0; r < 16; ++r) {
      const float e = exp2f(s[r] * sc);
      lsum[r] += e;
      const int row = (r & 3) + ((r >> 2) << 3) + (hl << 2);
      Pb[w][row][l31] = f2bf(e);
    }
    const short8 vb = *(const short8*)&Vt[l15][kc + (quad << 3)];
#pragma unroll
    for (int tt = 0; tt < 2; ++tt) {
      const short8 pa = *(const short8*)&Pb[w][(tt << 4) + l15][quad << 3];
      acco[tt] =
          __builtin_amdgcn_mfma_f32_16x16x32_bf16(pa, vb, acco[tt], 0, 0, 0);
    }
  }

  // butterfly-reduce lsum across the 32 lanes of each half (rows disjoint)
#pragma unroll
  for (int r = 0; r < 16; ++r) {
    float lv = lsum[r];
    lv += __shfl_xor(lv, 1, 64);
    lv += __shfl_xor(lv, 2, 64);
    lv += __shfl_xor(lv, 4, 64);
    lv += __shfl_xor(lv, 8, 64);
    lv += __shfl_xor(lv, 16, 64);
    lsum[r] = lv;
  }
  {
    const int rr = l31;
    if (((rr >> 2) & 1) == hl) {
      const int reg = (rr & 3) + ((rr >> 3) << 2);
      lb[w][rr] = 1.0f / lsum[reg];
    }
  }
  // O epilogue: C/D 16x16 layout col=l15=d, row=quad*4+r
#pragma unroll
  for (int tt = 0; tt < 2; ++tt) {
#pragma unroll
    for (int r = 0; r < 4; ++r) {
      const int nloc = (tt << 4) + (quad << 2) + r;
      const float val = acco[tt][r] * lb[w][nloc];
      const int n = row0 + nloc;
      out2[(((b << 10) + n) << 8) + (h << 4) + l15] = val;
    }
  }
}

// ---------------------------------------------------------------------------
// Final linear (unchanged, passed R2/R3).
// ---------------------------------------------------------------------------
__global__ __launch_bounds__(256) void linear_kernel(
    const float* __restrict__ inp, const float* __restrict__ wpT,
    void* __restrict__ out, const int* __restrict__ flag) {
  __shared__ float As[16][64];
  __shared__ float Bs[16][64];
  const int isf32 = *flag;
  const int t   = threadIdx.x;
  const int m0  = blockIdx.x << 6;
  const int co0 = blockIdx.y << 6;
  const int tx = t & 15, ty = t >> 4;
  const int pA = t >> 2, cgA = (t & 3) << 2;
  const int ciB = t >> 4, co4B = (t & 15) << 2;
  float acc[4][4] = {{0.f, 0.f, 0.f, 0.f}};
  for (int c0 = 0; c0 < DIM; c0 += 16) {
    const float4 av = *(const float4*)&inp[(m0 + pA) * DIM + c0 + cgA];
    const float4 bv = *(const float4*)&wpT[(c0 + ciB) * DIM + co0 + co4B];
    __syncthreads();
    As[cgA + 0][pA] = av.x;
    As[cgA + 1][pA] = av.y;
    As[cgA + 2][pA] = av.z;
    As[cgA + 3][pA] = av.w;
    *(float4*)&Bs[ciB][co4B] = bv;
    __syncthreads();
#pragma unroll
    for (int kk = 0; kk < 16; ++kk) {
      const float4 a  = *(const float4*)&As[kk][tx << 2];
      const float4 bb = *(const float4*)&Bs[kk][ty << 2];
      acc[0][0] += a.x * bb.x; acc[0][1] += a.x * bb.y;
      acc[0][2] += a.x * bb.z; acc[0][3] += a.x * bb.w;
      acc[1][0] += a.y * bb.x; acc[1][1] += a.y * bb.y;
      acc[1][2] += a.y * bb.z; acc[1][3] += a.y * bb.w;
      acc[2][0] += a.z * bb.x; acc[2][1] += a.z * bb.y;
      acc[2][2] += a.z * bb.z; acc[2][3] += a.z * bb.w;
      acc[3][0] += a.w * bb.x; acc[3][1] += a.w * bb.y;
      acc[3][2] += a.w * bb.z; acc[3][3] += a.w * bb.w;
    }
  }
  const int row = m0 + (tx << 2);
  if (!isf32) {
    unsigned short* o16 = (unsigned short*)out;
#pragma unroll
    for (int i = 0; i < 4; ++i) {
      ushort4 sv;
      sv.x = f2bf(acc[i][0]); sv.y = f2bf(acc[i][1]);
      sv.z = f2bf(acc[i][2]); sv.w = f2bf(acc[i][3]);
      *(ushort4*)&o16[(row + i) * DIM + co0 + (ty << 2)] = sv;
    }
  } else {
    float* o32 = (float*)out;
#pragma unroll
    for (int i = 0; i < 4; ++i) {
      *(float4*)&o32[(row + i) * DIM + co0 + (ty << 2)] =
          make_float4(acc[i][0], acc[i][1], acc[i][2], acc[i][3]);
    }
  }
}

// ---------------------------------------------------------------------------
extern "C" void kernel_launch(void* const* d_in, const int* in_sizes, int n_in,
                              void* d_out, int out_size, void* d_ws,
                              size_t ws_size, hipStream_t stream) {
  const void* x  = d_in[0];
  const void* w3 = d_in[1];
  const void* b3 = d_in[2];
  const void* w5 = d_in[3];
  const void* b5 = d_in[4];
  const void* w7 = d_in[5];
  const void* b7 = d_in[6];
  const void* wp = d_in[7];

  char* p = (char*)d_ws;
  int* flag = (int*)p;                       p += 256;
  unsigned short* xbf = (unsigned short*)p;  p += 4u * 1024 * 1024;
  unsigned short* wB3 = (unsigned short*)p;  p += 131072;
  unsigned short* wB5 = (unsigned short*)p;  p += 1179648;
  unsigned short* wB7 = (unsigned short*)p;  p += 3276800;
  float* wpT = (float*)p;                    p += 262144;
  float* b3c = (float*)p;                    p += 1024;
  float* b5c = (float*)p;                    p += 1024;
  float* b7c = (float*)p;                    p += 1024;
  unsigned short* qc = (unsigned short*)p;   p += 4194304;  // bf16 QK layout
  unsigned short* kT = (unsigned short*)p;   p += 4194304;  // bf16 QK layout
  unsigned short* vT = (unsigned short*)p;   p += 4194304;  // bf16 V^T layout
  float* o2  = (float*)p;                    p += 8388608;  // fp32 [8192][256]

  detect_kernel<<<1, 256, 0, stream>>>((const unsigned short*)x, flag);

  xconv_kernel<<<2048, 256, 0, stream>>>(x, xbf, flag);
  wbconv_kernel<<<256, 256, 0, stream>>>(w3, wB3, 1, flag);
  wbconv_kernel<<<2304, 256, 0, stream>>>(w5, wB5, 9, flag);
  wbconv_kernel<<<6400, 256, 0, stream>>>(w7, wB7, 25, flag);
  wtrans_kernel<<<256, 256, 0, stream>>>(wp, wpT, flag);
  convert_kernel<<<1, 256, 0, stream>>>(b3, b3c, 256, flag);
  convert_kernel<<<1, 256, 0, stream>>>(b5, b5c, 256, flag);
  convert_kernel<<<1, 256, 0, stream>>>(b7, b7c, 256, flag);

  dim3 cg(128, 4);
  conv_mfma_kernel<1, 0><<<cg, 256, 0, stream>>>(xbf, wB3, b3c, qc);  // q
  conv_mfma_kernel<3, 1><<<cg, 256, 0, stream>>>(xbf, wB5, b5c, vT);  // v
  conv_mfma_kernel<5, 0><<<cg, 256, 0, stream>>>(xbf, wB7, b7c, kT);  // k

  attn_mfma_kernel<<<1024, 256, 0, stream>>>(qc, kT, vT, o2);

  dim3 lg(128, 4);
  linear_kernel<<<lg, 256, 0, stream>>>(o2, wpT, d_out, flag);
}

// Round 6
// 265.130 us; speedup vs baseline: 3.8742x; 1.1634x over previous
//
#include <hip/hip_runtime.h>
#include <hip/hip_bf16.h>

#define DIM 256
#define HW  1024  // 32*32

typedef __attribute__((ext_vector_type(8))) short short8;
typedef __attribute__((ext_vector_type(4))) float floatx4;
typedef __attribute__((ext_vector_type(16))) float floatx16;

__device__ inline unsigned short f2bf(float f) {
  union { float f; unsigned u; } v;
  v.f = f;
  unsigned u = v.u;
  u += 0x7fffu + ((u >> 16) & 1u);
  return (unsigned short)(u >> 16);
}

// ---------------------------------------------------------------------------
// Dtype detector: flag=1 if inputs are fp32, 0 if bf16 (see R2 notes).
// ---------------------------------------------------------------------------
__global__ void detect_kernel(const unsigned short* __restrict__ xr,
                              int* __restrict__ flag) {
  __shared__ int cnt;
  if (threadIdx.x == 0) cnt = 0;
  __syncthreads();
  int local = 0;
  for (int i = threadIdx.x; i < 8192; i += 256) {
    unsigned short u = xr[i];
    if ((u & 0x7F80u) == 0x7F80u) local++;
  }
  if (local) atomicAdd(&cnt, local);
  __syncthreads();
  if (threadIdx.x == 0) *flag = (cnt > 0) ? 1 : 0;
}

__device__ inline float ldin(const void* p, long i, int isf32) {
  if (isf32) return ((const float*)p)[i];
  union { unsigned u; float f; } v;
  v.u = ((unsigned)((const unsigned short*)p)[i]) << 16;
  return v.f;
}

// ---------------------------------------------------------------------------
// Fused prep kernel (one launch): x->bf16, conv/wp weights -> MFMA-fragment
// order bf16, biases -> fp32.
// wF layout: [tap][c8(8)][co16(16)][lane(64)][j(8)]  where
//   co = co16*16 + (lane&15), ci = c8*32 + (lane>>4)*8 + j
// so a wave's B-fragment load is 64 lanes x 16B contiguous (1KB, coalesced).
// ---------------------------------------------------------------------------
__device__ inline void frag_repack(const void* __restrict__ w,
                                   unsigned short* __restrict__ wF, int KK,
                                   int local_blk, int t, int isf32) {
  const int idx = local_blk * 256 + t;
  const int j    = idx & 7;
  const int lane = (idx >> 3) & 63;
  const int co16 = (idx >> 9) & 15;
  const int c8   = (idx >> 13) & 7;
  const int tap  = idx >> 16;
  const int co = (co16 << 4) | (lane & 15);
  const int ci = (c8 << 5) + ((lane >> 4) << 3) + j;
  wF[idx] = f2bf(ldin(w, (long)(co * 256 + ci) * KK + tap, isf32));
}

__global__ void prep_kernel(const void* __restrict__ x,
                            const void* __restrict__ w3,
                            const void* __restrict__ b3,
                            const void* __restrict__ w5,
                            const void* __restrict__ b5,
                            const void* __restrict__ w7,
                            const void* __restrict__ b7,
                            const void* __restrict__ wp,
                            unsigned short* __restrict__ xbf,
                            unsigned short* __restrict__ wF3,
                            unsigned short* __restrict__ wF5,
                            unsigned short* __restrict__ wF7,
                            unsigned short* __restrict__ wpF,
                            float* __restrict__ bc,  // [3][256]
                            const int* __restrict__ flag) {
  const int isf32 = *flag;
  const int bid = blockIdx.x;
  const int t = threadIdx.x;
  if (bid < 2048) {            // x -> bf16, 4 elem/thread
    const int i = (bid * 256 + t) * 4;
    if (isf32) {
      const float4 v = *(const float4*)((const float*)x + i);
      ushort4 o;
      o.x = f2bf(v.x); o.y = f2bf(v.y); o.z = f2bf(v.z); o.w = f2bf(v.w);
      *(ushort4*)(xbf + i) = o;
    } else {
      *(ushort4*)(xbf + i) = *(const ushort4*)((const unsigned short*)x + i);
    }
  } else if (bid < 2304) {
    frag_repack(w3, wF3, 1, bid - 2048, t, isf32);
  } else if (bid < 4608) {
    frag_repack(w5, wF5, 9, bid - 2304, t, isf32);
  } else if (bid < 11008) {
    frag_repack(w7, wF7, 25, bid - 4608, t, isf32);
  } else if (bid < 11264) {
    frag_repack(wp, wpF, 1, bid - 11008, t, isf32);
  } else {                     // biases: 768 elements
#pragma unroll
    for (int r = 0; r < 3; ++r) {
      const int i = r * 256 + t;
      const void* src = (i < 256) ? b3 : (i < 512) ? b5 : b7;
      bc[i] = ldin(src, i & 255, isf32);
    }
  }
}

// ---------------------------------------------------------------------------
// MFMA implicit-GEMM conv, SAME padding, stride 1, bf16 in / bf16 out.
// Restructured (R6): halo x-tile staged in LDS once per ci-chunk; full tap
// loop runs barrier-free with A from LDS (tap-shifted) and B straight from
// global in fragment order. 16 barriers total (was 400).
//   xbf : [8][32][32][256] bf16 NHWC
//   wF  : fragment order (see prep)
// Attention coords (R2-verified): slab=(b<<4)+(co>>4),
//   m = (co&15)*64 + (n>>4), d = n&15   [m*16+d == (co&15)*1024 + n]
//   out : TSTORE==0 -> QK rows  [slab][m][16d]: (slab<<14)+((co&15)<<10)+n
//         TSTORE==1 -> V^T      [slab][d][1024m]:
//                      (slab<<14)+((n&15)<<10)+((co&15)<<6)+(n>>4)
// Block: 256 thr = 4 waves; tile 64 pos (2 rows x 32 cols) x 64 co.
// ---------------------------------------------------------------------------
template <int KS, int TSTORE>
__global__ __launch_bounds__(256) void conv_mfma_kernel(
    const unsigned short* __restrict__ xbf,
    const unsigned short* __restrict__ wF,
    const float* __restrict__ bias, unsigned short* __restrict__ out) {
  constexpr int P = KS / 2;
  constexpr int HR = 2 + 2 * P;    // halo rows
  constexpr int WC = 32 + 2 * P;   // halo cols
  constexpr int CELLS = HR * WC;
  constexpr int LOADS = CELLS * 4; // 4 x uint4 (8 bf16) per cell
  constexpr int ROUNDS = (LOADS + 255) / 256;
  __shared__ unsigned short Xs[CELLS * 40];  // [cell][32ci pad40] (2-way=free)
  const int t   = threadIdx.x;
  const int m0  = blockIdx.x << 6;
  const int b   = m0 >> 10;
  const int n0  = m0 & 1023;
  const int r0  = n0 >> 5;         // first of 2 image rows
  const int co0 = blockIdx.y << 6;
  const int wv   = t >> 6;
  const int lane = t & 63;
  const int wm = (wv & 1) << 5;
  const int wn = (wv >> 1) << 5;
  const int l15  = lane & 15;
  const int quad = lane >> 4;
  const int rbase = wm >> 5;       // 0 or 1 (image row within tile)
  const int cogb  = (co0 >> 4) + (wn >> 4);  // co16-tile index base

  floatx4 acc[2][2] = {};

  for (int c8 = 0; c8 < 8; ++c8) {
    __syncthreads();  // all waves done reading previous chunk
#pragma unroll
    for (int rr = 0; rr < ROUNDS; ++rr) {
      const int id = rr * 256 + t;
      if (ROUNDS * 256 == LOADS || id < LOADS) {
        const int cell = id >> 2;
        const int part = id & 3;
        const int hr = cell / WC;
        const int wc = cell - hr * WC;
        const int xr = r0 + hr - P;
        const int xc = wc - P;
        uint4 v = make_uint4(0, 0, 0, 0);
        if (((unsigned)xr < 32u) && ((unsigned)xc < 32u))
          v = *(const uint4*)&xbf[(((b * 32 + xr) * 32 + xc) << 8) +
                                  (c8 << 5) + (part << 3)];
        *(uint4*)&Xs[cell * 40 + (part << 3)] = v;
      }
    }
    __syncthreads();
#pragma unroll
    for (int kh = 0; kh < KS; ++kh) {
#pragma unroll
      for (int kw = 0; kw < KS; ++kw) {
        constexpr int T8 = 8;
        const int tap = kh * KS + kw;
        const unsigned short* wptr =
            &wF[((((tap << 3) + c8) << 4) + cogb) * 512 + (lane << 3)];
        const short8 bfr0 = *(const short8*)wptr;
        const short8 bfr1 = *(const short8*)(wptr + 512);
        const unsigned short* xs =
            &Xs[((rbase + kh) * WC + l15 + kw) * 40 + (quad << 3)];
        const short8 afr0 = *(const short8*)xs;
        const short8 afr1 = *(const short8*)(xs + 16 * 40);
        acc[0][0] = __builtin_amdgcn_mfma_f32_16x16x32_bf16(afr0, bfr0,
                                                            acc[0][0], 0, 0, 0);
        acc[0][1] = __builtin_amdgcn_mfma_f32_16x16x32_bf16(afr0, bfr1,
                                                            acc[0][1], 0, 0, 0);
        acc[1][0] = __builtin_amdgcn_mfma_f32_16x16x32_bf16(afr1, bfr0,
                                                            acc[1][0], 0, 0, 0);
        acc[1][1] = __builtin_amdgcn_mfma_f32_16x16x32_bf16(afr1, bfr1,
                                                            acc[1][1], 0, 0, 0);
        (void)T8;
      }
    }
  }
  // epilogue: C/D layout col=l15 (co), row=quad*4+reg (position)  [R5-verified]
#pragma unroll
  for (int mi = 0; mi < 2; ++mi) {
#pragma unroll
    for (int ni = 0; ni < 2; ++ni) {
      const int co = co0 + wn + (ni << 4) + l15;
      const float bj = bias[co];
      const int nb = n0 + wm + (mi << 4) + (quad << 2);
      const int slab = (b << 4) + (co >> 4);
      const int clo = co & 15;
      floatx4 a = acc[mi][ni];
      if (TSTORE == 0) {
        ushort4 pk;
        pk.x = f2bf(a[0] + bj); pk.y = f2bf(a[1] + bj);
        pk.z = f2bf(a[2] + bj); pk.w = f2bf(a[3] + bj);
        *(ushort4*)&out[(slab << 14) + (clo << 10) + nb] = pk;
      } else {
        const int base = (slab << 14) + (clo << 6);
#pragma unroll
        for (int i = 0; i < 4; ++i) {
          const int n = nb + i;
          out[base + ((n & 15) << 10) + (n >> 4)] = f2bf(a[i] + bj);
        }
      }
    }
  }
}

// ---------------------------------------------------------------------------
// MFMA attention per (b,h) slab: softmax(Q K^T * 0.25) V.  [R5-verified]
//   qg, kg : bf16 [slab][1024 m][16 d];  vg : bf16 [slab][16 d][1024 m]
//   out2   : bf16 [8][1024 m][256], c = h*16+d   (now bf16 for MFMA linear)
// ---------------------------------------------------------------------------
__global__ __launch_bounds__(256) void attn_mfma_kernel(
    const unsigned short* __restrict__ qg,
    const unsigned short* __restrict__ kg,
    const unsigned short* __restrict__ vg,
    unsigned short* __restrict__ out2) {
  __shared__ __align__(16) unsigned short Kc[16384];     // [key][16]
  __shared__ __align__(16) unsigned short Vt[16][1032];  // [d][key], padded
  __shared__ __align__(16) unsigned short Pb[4][32][40]; // per-wave P
  __shared__ float lb[4][32];
  const int t    = threadIdx.x;
  const int w    = t >> 6;
  const int lane = t & 63;
  const int slab = blockIdx.x >> 3;
  const int rb   = blockIdx.x & 7;
  const int b = slab >> 4;
  const int h = slab & 15;
  const int l31  = lane & 31;
  const int hl   = lane >> 5;
  const int l15  = lane & 15;
  const int quad = lane >> 4;

#pragma unroll
  for (int j = 0; j < 8; ++j) {
    const int id = (j << 8) + t;
    const int e  = id << 3;
    *(uint4*)&Kc[e] = *(const uint4*)&kg[(slab << 14) + e];
    const int d = e >> 10, ky = e & 1023;
    *(uint4*)&Vt[d][ky] = *(const uint4*)&vg[(slab << 14) + e];
  }

  const int row0 = (rb << 7) + (w << 5);
  const short8 qa =
      *(const short8*)&qg[(slab << 14) + ((row0 + l31) << 4) + (hl << 3)];

  float lsum[16] = {};
  floatx4 acco[2] = {};
  const float sc = 0.25f * 1.4426950408889634f;

  __syncthreads();

  for (int kc = 0; kc < 1024; kc += 32) {
    const short8 kb = *(const short8*)&Kc[((kc + l31) << 4) + (hl << 3)];
    floatx16 s = {};
    s = __builtin_amdgcn_mfma_f32_32x32x16_bf16(qa, kb, s, 0, 0, 0);
#pragma unroll
    for (int r = 0; r < 16; ++r) {
      const float e = exp2f(s[r] * sc);
      lsum[r] += e;
      const int row = (r & 3) + ((r >> 2) << 3) + (hl << 2);
      Pb[w][row][l31] = f2bf(e);
    }
    const short8 vb = *(const short8*)&Vt[l15][kc + (quad << 3)];
#pragma unroll
    for (int tt = 0; tt < 2; ++tt) {
      const short8 pa = *(const short8*)&Pb[w][(tt << 4) + l15][quad << 3];
      acco[tt] =
          __builtin_amdgcn_mfma_f32_16x16x32_bf16(pa, vb, acco[tt], 0, 0, 0);
    }
  }

#pragma unroll
  for (int r = 0; r < 16; ++r) {
    float lv = lsum[r];
    lv += __shfl_xor(lv, 1, 64);
    lv += __shfl_xor(lv, 2, 64);
    lv += __shfl_xor(lv, 4, 64);
    lv += __shfl_xor(lv, 8, 64);
    lv += __shfl_xor(lv, 16, 64);
    lsum[r] = lv;
  }
  {
    const int rr = l31;
    if (((rr >> 2) & 1) == hl) {
      const int reg = (rr & 3) + ((rr >> 3) << 2);
      lb[w][rr] = 1.0f / lsum[reg];
    }
  }
#pragma unroll
  for (int tt = 0; tt < 2; ++tt) {
#pragma unroll
    for (int r = 0; r < 4; ++r) {
      const int nloc = (tt << 4) + (quad << 2) + r;
      const float val = acco[tt][r] * lb[w][nloc];
      const int n = row0 + nloc;
      out2[(((b << 10) + n) << 8) + (h << 4) + l15] = f2bf(val);
    }
  }
}

// ---------------------------------------------------------------------------
// Final linear, MFMA bf16: y[m][co] = sum_ci o2b[m][ci] * wp[co][ci].
// B (wp) comes fragment-packed from prep (wpF, tap=0/KK=1 format).
// ---------------------------------------------------------------------------
__global__ __launch_bounds__(256) void linear_mfma_kernel(
    const unsigned short* __restrict__ inp,  // bf16 [8192][256]
    const unsigned short* __restrict__ wpF,  // fragment order
    void* __restrict__ out, const int* __restrict__ flag) {
  __shared__ unsigned short As[64 * 40];
  const int isf32 = *flag;
  const int t   = threadIdx.x;
  const int m0  = blockIdx.x << 6;
  const int co0 = blockIdx.y << 6;
  const int wv   = t >> 6;
  const int lane = t & 63;
  const int wm = (wv & 1) << 5;
  const int wn = (wv >> 1) << 5;
  const int l15  = lane & 15;
  const int quad = lane >> 4;
  const int cogb = (co0 >> 4) + (wn >> 4);
  const int rowS = t >> 2;
  const int partS = t & 3;

  floatx4 acc[2][2] = {};

  for (int c8 = 0; c8 < 8; ++c8) {
    const uint4 v = *(const uint4*)&inp[((m0 + rowS) << 8) + (c8 << 5) +
                                        (partS << 3)];
    __syncthreads();
    *(uint4*)&As[rowS * 40 + (partS << 3)] = v;
    __syncthreads();
    const unsigned short* wptr = &wpF[(((c8 << 4) + cogb) << 9) + (lane << 3)];
    const short8 bfr0 = *(const short8*)wptr;
    const short8 bfr1 = *(const short8*)(wptr + 512);
    const unsigned short* xs = &As[(wm + l15) * 40 + (quad << 3)];
    const short8 afr0 = *(const short8*)xs;
    const short8 afr1 = *(const short8*)(xs + 16 * 40);
    acc[0][0] = __builtin_amdgcn_mfma_f32_16x16x32_bf16(afr0, bfr0,
                                                        acc[0][0], 0, 0, 0);
    acc[0][1] = __builtin_amdgcn_mfma_f32_16x16x32_bf16(afr0, bfr1,
                                                        acc[0][1], 0, 0, 0);
    acc[1][0] = __builtin_amdgcn_mfma_f32_16x16x32_bf16(afr1, bfr0,
                                                        acc[1][0], 0, 0, 0);
    acc[1][1] = __builtin_amdgcn_mfma_f32_16x16x32_bf16(afr1, bfr1,
                                                        acc[1][1], 0, 0, 0);
  }
  // epilogue: m = m0+wm+mi*16+quad*4+r, co = co0+wn+ni*16+l15
#pragma unroll
  for (int mi = 0; mi < 2; ++mi) {
#pragma unroll
    for (int ni = 0; ni < 2; ++ni) {
      const int co = co0 + wn + (ni << 4) + l15;
      const int mb = m0 + wm + (mi << 4) + (quad << 2);
      floatx4 a = acc[mi][ni];
      if (!isf32) {
        unsigned short* o16 = (unsigned short*)out;
#pragma unroll
        for (int r = 0; r < 4; ++r) o16[(mb + r) * 256 + co] = f2bf(a[r]);
      } else {
        float* o32 = (float*)out;
#pragma unroll
        for (int r = 0; r < 4; ++r) o32[(mb + r) * 256 + co] = a[r];
      }
    }
  }
}

// ---------------------------------------------------------------------------
extern "C" void kernel_launch(void* const* d_in, const int* in_sizes, int n_in,
                              void* d_out, int out_size, void* d_ws,
                              size_t ws_size, hipStream_t stream) {
  const void* x  = d_in[0];
  const void* w3 = d_in[1];
  const void* b3 = d_in[2];
  const void* w5 = d_in[3];
  const void* b5 = d_in[4];
  const void* w7 = d_in[5];
  const void* b7 = d_in[6];
  const void* wp = d_in[7];

  char* p = (char*)d_ws;
  int* flag = (int*)p;                       p += 256;
  unsigned short* xbf = (unsigned short*)p;  p += 4u * 1024 * 1024;
  unsigned short* wF3 = (unsigned short*)p;  p += 131072;
  unsigned short* wF5 = (unsigned short*)p;  p += 1179648;
  unsigned short* wF7 = (unsigned short*)p;  p += 3276800;
  unsigned short* wpF = (unsigned short*)p;  p += 131072;
  float* bc = (float*)p;                     p += 4096;     // [3][256]
  unsigned short* qc  = (unsigned short*)p;  p += 4194304;  // bf16 QK rows
  unsigned short* kT  = (unsigned short*)p;  p += 4194304;  // bf16 QK rows
  unsigned short* vT  = (unsigned short*)p;  p += 4194304;  // bf16 V^T
  unsigned short* o2b = (unsigned short*)p;  p += 4194304;  // bf16 [8192][256]

  detect_kernel<<<1, 256, 0, stream>>>((const unsigned short*)x, flag);

  prep_kernel<<<11265, 256, 0, stream>>>(x, w3, b3, w5, b5, w7, b7, wp, xbf,
                                         wF3, wF5, wF7, wpF, bc, flag);

  dim3 cg(128, 4);
  conv_mfma_kernel<1, 0><<<cg, 256, 0, stream>>>(xbf, wF3, bc, qc);        // q
  conv_mfma_kernel<3, 1><<<cg, 256, 0, stream>>>(xbf, wF5, bc + 256, vT);  // v
  conv_mfma_kernel<5, 0><<<cg, 256, 0, stream>>>(xbf, wF7, bc + 512, kT);  // k

  attn_mfma_kernel<<<1024, 256, 0, stream>>>(qc, kT, vT, o2b);

  dim3 lg(128, 4);
  linear_mfma_kernel<<<lg, 256, 0, stream>>>(o2b, wpF, d_out, flag);
}